// Round 13
// baseline (341.036 us; speedup 1.0000x reference)
//
#include <hip/hip_runtime.h>
#include <hip/hip_bf16.h>

#define TPB 256
#define NB_E 32          // edge chunks for counting sort
#define HTPB 512         // threads per hist/scatter block
#define NHALF_LDS 10240  // LDS histogram capacity (ints) per half-range
#define ASHIFT 11        // src-chunk = src >> 11  (2048 nodes/chunk)
#define NBLK_A 64        // blocks for src-chunk radix pass

typedef __attribute__((ext_vector_type(8))) short bf16x8_t;
typedef __attribute__((ext_vector_type(4))) float f32x4_t;
typedef __attribute__((ext_vector_type(8))) unsigned short u16x8_t;
typedef __attribute__((ext_vector_type(4))) unsigned short u16x4_t;

__device__ __forceinline__ float bf2f(unsigned short u) {
    return __uint_as_float(((unsigned)u) << 16);
}
__device__ __forceinline__ unsigned short f2bf(float f) {
    unsigned x = __float_as_uint(f);
    unsigned r = (x + 0x7fff + ((x >> 16) & 1)) >> 16;  // RNE
    return (unsigned short)r;
}

// async global -> LDS, 16 bytes per lane
__device__ __forceinline__ void gload16(const unsigned short* g, unsigned short* l) {
    __builtin_amdgcn_global_load_lds(
        (const __attribute__((address_space(1))) unsigned int*)(const void*)g,
        (__attribute__((address_space(3))) unsigned int*)(void*)l, 16, 0, 0);
}

// ---------------- pass A: sort edges by src-chunk (radix, no global atomics) ----------------

__global__ __launch_bounds__(1024) void sortA_count(const int* __restrict__ src,
                                                    int* __restrict__ cnt, int E, int nch, int chunkE) {
    __shared__ int h[16];
    if (threadIdx.x < 16) h[threadIdx.x] = 0;
    __syncthreads();
    int b = blockIdx.x;
    int beg = b * chunkE, end = min(E, beg + chunkE);
    for (int i = beg + threadIdx.x; i < end; i += 1024)
        atomicAdd(&h[src[i] >> ASHIFT], 1);
    __syncthreads();
    if (threadIdx.x < nch) cnt[threadIdx.x * NBLK_A + b] = h[threadIdx.x];
}

// exclusive scan of cnt[0..n) in place, single block (n <= 1024)
__global__ __launch_bounds__(1024) void sortA_scan(int* __restrict__ cnt, int n) {
    __shared__ int buf[1024];
    int v = (threadIdx.x < n) ? cnt[threadIdx.x] : 0;
    buf[threadIdx.x] = v;
    __syncthreads();
    for (int off = 1; off < 1024; off <<= 1) {
        int t = (threadIdx.x >= off) ? buf[threadIdx.x - off] : 0;
        __syncthreads();
        buf[threadIdx.x] += t;
        __syncthreads();
    }
    if (threadIdx.x < n) cnt[threadIdx.x] = buf[threadIdx.x] - v;  // exclusive
}

__global__ __launch_bounds__(1024) void sortA_scatter(const int* __restrict__ src,
                                                      const int* __restrict__ dst,
                                                      const int* __restrict__ cnt,
                                                      int* __restrict__ src2, int* __restrict__ dst2,
                                                      int E, int nch, int chunkE) {
    __shared__ int base[16];
    __shared__ int rnk[16];
    int b = blockIdx.x;
    if (threadIdx.x < nch) {
        base[threadIdx.x] = cnt[threadIdx.x * NBLK_A + b];
        rnk[threadIdx.x] = 0;
    }
    __syncthreads();
    int beg = b * chunkE, end = min(E, beg + chunkE);
    for (int i = beg + threadIdx.x; i < end; i += 1024) {
        int s = src[i], d = dst[i];
        int c = s >> ASHIFT;
        int r = atomicAdd(&rnk[c], 1);
        int pos = base[c] + r;
        src2[pos] = s;
        dst2[pos] = d;
    }
}

// ---------------- CSR build via counting sort (no global atomics) ----------------

__global__ __launch_bounds__(HTPB) void hist_kernel(
    const int* __restrict__ src, const int* __restrict__ dst,
    int* __restrict__ histD, int* __restrict__ histS,
    int E, int N, int nhalf, int chunk) {
    __shared__ int h[NHALF_LDS];
    int b = blockIdx.x, var = blockIdx.y;
    const int* arr = (var < 2) ? dst : src;
    int lo = (var & 1) * nhalf;
    int hi = min(lo + nhalf, N);
    int cnt = hi - lo;
    for (int i = threadIdx.x; i < cnt; i += HTPB) h[i] = 0;
    __syncthreads();
    int beg = b * chunk, end = min(E, beg + chunk);
    for (int i = beg + threadIdx.x; i < end; i += HTPB) {
        int v = arr[i];
        if (v >= lo && v < hi) atomicAdd(&h[v - lo], 1);
    }
    __syncthreads();
    int* out = ((var < 2) ? histD : histS) + (size_t)b * N + lo;
    for (int i = threadIdx.x; i < cnt; i += HTPB) out[i] = h[i];
}

__global__ void degreduce_kernel(const int* __restrict__ histD, const int* __restrict__ histS,
                                 float* __restrict__ ns, float* __restrict__ nd,
                                 int* __restrict__ degp, int N) {
    int n = blockIdx.x * blockDim.x + threadIdx.x;
    if (n >= N) return;
    int di = 0, dout = 0;
    for (int b = 0; b < NB_E; b++) {
        di += histD[(size_t)b * N + n];
        dout += histS[(size_t)b * N + n];
    }
    nd[n] = di > 0 ? rsqrtf((float)di) : 0.f;
    ns[n] = dout > 0 ? rsqrtf((float)dout) : 0.f;
    degp[n] = (di + 7) & ~7;  // pad each list to multiple of 8
}

__global__ __launch_bounds__(1024) void scan1(const int* __restrict__ degp,
                                              int* __restrict__ rp, int* __restrict__ bsum, int n) {
    __shared__ int buf[1024];
    int b = blockIdx.x;
    int i = b * 1024 + threadIdx.x;
    int v = (i < n) ? degp[i] : 0;
    buf[threadIdx.x] = v;
    __syncthreads();
    for (int off = 1; off < 1024; off <<= 1) {
        int t = (threadIdx.x >= off) ? buf[threadIdx.x - off] : 0;
        __syncthreads();
        buf[threadIdx.x] += t;
        __syncthreads();
    }
    if (i < n) rp[i + 1] = buf[threadIdx.x];
    if (threadIdx.x == 1023) bsum[b] = buf[1023];
    if (b == 0 && threadIdx.x == 0) rp[0] = 0;
}

__global__ void scan2(int* __restrict__ bsum, int nb) {
    int lane = threadIdx.x;
    int v = (lane < nb) ? bsum[lane] : 0;
    for (int off = 1; off < 64; off <<= 1) {
        int t = __shfl_up(v, off);
        if (lane >= off) v += t;
    }
    if (lane < nb) bsum[lane] = v;
}

__global__ __launch_bounds__(1024) void scan3(int* __restrict__ rp, const int* __restrict__ bsum, int n) {
    int b = blockIdx.x;
    if (b == 0) return;
    int i = b * 1024 + threadIdx.x;
    if (i < n) rp[i + 1] += bsum[b - 1];
}

__global__ void gbase_kernel(const int* __restrict__ histD, const int* __restrict__ rp,
                             int* __restrict__ gbase, int N) {
    int n = blockIdx.x * blockDim.x + threadIdx.x;
    if (n >= N) return;
    int run = rp[n];
    for (int b = 0; b < NB_E; b++) {
        gbase[(size_t)b * N + n] = run;
        run += histD[(size_t)b * N + n];
    }
}

__global__ __launch_bounds__(HTPB) void scatter2_kernel(
    const int* __restrict__ src, const int* __restrict__ dst,
    const int* __restrict__ gbase, const float* __restrict__ ns,
    int2* __restrict__ payload, int E, int N, int nhalf, int chunk) {
    __shared__ int h[NHALF_LDS];
    int b = blockIdx.x, half = blockIdx.y;
    int lo = half * nhalf;
    int hi = min(lo + nhalf, N);
    int cnt = hi - lo;
    for (int i = threadIdx.x; i < cnt; i += HTPB) h[i] = 0;
    __syncthreads();
    int beg = b * chunk, end = min(E, beg + chunk);
    for (int i = beg + threadIdx.x; i < end; i += HTPB) {
        int d = dst[i];
        if (d >= lo && d < hi) {
            int s = src[i];
            int rank = atomicAdd(&h[d - lo], 1);
            int pos = gbase[(size_t)b * N + d] + rank;
            payload[pos] = make_int2(s, __float_as_int(ns[s]));
        }
    }
}

// t[d] = nd[d] * sum_e w_e   (padding has w=0)
__global__ __launch_bounds__(256) void st_kernel(const int* __restrict__ rp,
                                                 const int2* __restrict__ payload,
                                                 const float* __restrict__ nd,
                                                 float* __restrict__ tv, int n) {
    int d = blockIdx.x * 4 + (threadIdx.x >> 6);
    if (d >= n) return;
    int lane = threadIdx.x & 63;
    int beg = rp[d], end = rp[d + 1];
    float acc = 0.f;
    for (int e = beg + lane; e < end; e += 64) acc += __int_as_float(payload[e].y);
    for (int off = 32; off > 0; off >>= 1) acc += __shfl_down(acc, off);
    if (lane == 0) tv[d] = acc * nd[d];
}

// ---------------- small GEMV (fp32) ----------------

__global__ void gemv_rows_split(const float* __restrict__ vec, const float* __restrict__ Mat,
                                const float* __restrict__ bias, float* __restrict__ out,
                                int n, int nslices) {
    int j = blockIdx.x, slice = blockIdx.y;
    int len = (n + nslices - 1) / nslices;
    int beg = slice * len, end = min(n, beg + len);
    const float* row = Mat + (size_t)j * n;
    float s = 0.f;
    for (int i = beg + threadIdx.x; i < end; i += blockDim.x) s += vec[i] * row[i];
    __shared__ float red[TPB];
    red[threadIdx.x] = s;
    __syncthreads();
    for (int o = TPB / 2; o > 0; o >>= 1) {
        if (threadIdx.x < o) red[threadIdx.x] += red[threadIdx.x + o];
        __syncthreads();
    }
    if (threadIdx.x == 0) {
        float v = red[0] + ((slice == 0 && bias) ? bias[j] : 0.f);
        atomicAdd(&out[j], v);
    }
}

__global__ __launch_bounds__(64) void u_kernel(const float* __restrict__ ce, const float* __restrict__ W1,
                                               float* __restrict__ u, int FD, int IF) {
    int j = blockIdx.x;
    int lane = threadIdx.x;
    float s = 0.f;
    for (int i = lane; i < FD; i += 64) s += ce[i] * W1[(size_t)i * IF + j];
    for (int off = 32; off > 0; off >>= 1) s += __shfl_down(s, off);
    if (lane == 0) u[j] = s;
}

// ---------------- conversion kernels ----------------

__global__ void pad_convert4(const float* __restrict__ in, int icols, int irows,
                             unsigned short* __restrict__ out, int ocols, int orows, int cpr) {
    int idx = blockIdx.x * blockDim.x + threadIdx.x;
    int row = idx / cpr;
    int c4 = (idx - row * cpr) * 4;
    if (row >= orows) return;
    float4 v = make_float4(0.f, 0.f, 0.f, 0.f);
    if (row < irows && c4 < icols)
        v = *(const float4*)(in + (size_t)row * icols + c4);
    u16x4_t o;
    o[0] = f2bf(v.x); o[1] = f2bf(v.y); o[2] = f2bf(v.z); o[3] = f2bf(v.w);
    *(u16x4_t*)(out + (size_t)row * ocols + c4) = o;
}

__global__ void transpose_pad(const float* __restrict__ W, int rows, int cols, int ldw,
                              unsigned short* __restrict__ out, int orows, int ocols) {
    __shared__ float tile[32][33];
    int k0 = blockIdx.x * 32, n0 = blockIdx.y * 32;
    int tx = threadIdx.x, ty = threadIdx.y;  // 32 x 8
    for (int i = 0; i < 32; i += 8) {
        int k = k0 + ty + i, n = n0 + tx;
        tile[ty + i][tx] = (k < rows && n < cols) ? W[(size_t)k * ldw + n] : 0.f;
    }
    __syncthreads();
    for (int i = 0; i < 32; i += 8) {
        int n = n0 + ty + i, k = k0 + tx;
        if (n < orows && k < ocols) out[(size_t)n * ocols + k] = f2bf(tile[tx][ty + i]);
    }
}

// ---------------- bf16 MFMA GEMM (64x64 tile, high-occupancy TLP) ----------------
__global__ __launch_bounds__(256) void mfma_gemm(
    const unsigned short* __restrict__ A, const unsigned short* __restrict__ Bt,
    const float* __restrict__ bias, const float* __restrict__ rowscale,
    const float* __restrict__ tvec, const float* __restrict__ uvec,
    const float* __restrict__ w3, float* __restrict__ zout,
    unsigned short* __restrict__ C, int M, int Nn, int Kp, int Cld, int relu) {
    __shared__ unsigned short As[2][64 * 32];
    __shared__ unsigned short Bs[2][64 * 32];
    int tid = threadIdx.x;
    int lane = tid & 63;
    int wave = tid >> 6;
    int wm = wave >> 1, wn = wave & 1;  // 2x2 waves, each 32x32
    int lg = lane >> 4, lt = lane & 15;

    int nwg = gridDim.x * gridDim.y;
    int hid = blockIdx.y * gridDim.x + blockIdx.x;
    int q = nwg >> 3, r8 = nwg & 7;
    int xcd = hid & 7, pos = hid >> 3;
    int wg = (xcd < r8 ? xcd * (q + 1) : r8 * (q + 1) + (xcd - r8) * q) + pos;
    int row0 = (wg / gridDim.x) * 64, col0 = (wg % gridDim.x) * 64;

    f32x4_t acc[2][2] = {};

    int sr = tid >> 2, sc = tid & 3;
    int ssw = sc ^ ((sr >> 1) & 3);
    const unsigned short* gA = A + (size_t)(row0 + sr) * Kp + (ssw << 3);
    const unsigned short* gB = Bt + (size_t)(col0 + sr) * Kp + (ssw << 3);

    int nk = Kp >> 5;
    gload16(gA, As[0] + tid * 8);
    gload16(gB, Bs[0] + tid * 8);
    __syncthreads();

    int cur = 0;
    for (int kp = 0; kp < nk; kp++) {
        if (kp + 1 < nk) {
            int k0 = (kp + 1) << 5;
            gload16(gA + k0, As[cur ^ 1] + tid * 8);
            gload16(gB + k0, Bs[cur ^ 1] + tid * 8);
        }
        bf16x8_t af[2], bfr[2];
#pragma unroll
        for (int mi = 0; mi < 2; mi++) {
            int r = wm * 32 + mi * 16 + lt;
            int sw = lg ^ ((r >> 1) & 3);
            af[mi] = *(const bf16x8_t*)(As[cur] + r * 32 + sw * 8);
        }
#pragma unroll
        for (int ni = 0; ni < 2; ni++) {
            int r = wn * 32 + ni * 16 + lt;
            int sw = lg ^ ((r >> 1) & 3);
            bfr[ni] = *(const bf16x8_t*)(Bs[cur] + r * 32 + sw * 8);
        }
#pragma unroll
        for (int mi = 0; mi < 2; mi++)
#pragma unroll
            for (int ni = 0; ni < 2; ni++)
                acc[mi][ni] = __builtin_amdgcn_mfma_f32_16x16x32_bf16(af[mi], bfr[ni], acc[mi][ni], 0, 0, 0);
        __syncthreads();
        cur ^= 1;
    }

#pragma unroll
    for (int mi = 0; mi < 2; mi++) {
#pragma unroll
        for (int r = 0; r < 4; r++) {
            int row = row0 + wm * 32 + mi * 16 + lg * 4 + r;
            if (row >= M) continue;
            float rs = rowscale ? rowscale[row] : 1.f;
            float tvr = tvec ? tvec[row] : 0.f;
            float zp = 0.f;
#pragma unroll
            for (int ni = 0; ni < 2; ni++) {
                int colb = col0 + wn * 32 + ni * 16 + lt;
                float v = 0.f;
                if (colb < Nn) {
                    v = acc[mi][ni][r] * rs;
                    if (bias) v += bias[colb];
                    if (tvec) v += tvr * uvec[colb];
                    if (relu) v = fmaxf(v, 0.f);
                    if (w3) zp += v * w3[colb];
                }
                if (C) C[(size_t)row * Cld + colb] = f2bf(v);
            }
            if (w3) {
                zp += __shfl_xor(zp, 1);
                zp += __shfl_xor(zp, 2);
                zp += __shfl_xor(zp, 4);
                zp += __shfl_xor(zp, 8);
                if (lt == 0) atomicAdd(&zout[row], zp);
            }
        }
    }
}

// ---------------- SpMM (CSR gather, src-chunk-sorted payload, 8-edge unroll) ----------------

// Fp=512: one wave per node, u16x8 (16B/lane)
__global__ __launch_bounds__(256) void spmm_bf16_512(
    const int* __restrict__ rp, const int2* __restrict__ payload,
    const unsigned short* __restrict__ X, unsigned short* __restrict__ Y, int n) {
    int node = blockIdx.x * 4 + (threadIdx.x >> 6);
    if (node >= n) return;
    int lane = threadIdx.x & 63;
    const unsigned short* Xo = X + lane * 8;
    int beg = rp[node], end = rp[node + 1];
    float acc[8] = {};
    for (int e = beg; e < end; e += 8) {
        int2 p[8];
#pragma unroll
        for (int j = 0; j < 8; j++) p[j] = payload[e + j];
        u16x8_t v[8];
#pragma unroll
        for (int j = 0; j < 8; j++) v[j] = *(const u16x8_t*)(Xo + (size_t)p[j].x * 512);
#pragma unroll
        for (int j = 0; j < 8; j++) {
            float w = __int_as_float(p[j].y);
#pragma unroll
            for (int c = 0; c < 8; c++) acc[c] += w * bf2f(v[j][c]);
        }
    }
    u16x8_t o;
#pragma unroll
    for (int c = 0; c < 8; c++) o[c] = f2bf(acc[c]);
    *(u16x8_t*)(Y + (size_t)node * 512 + lane * 8) = o;
}

// Fp=256: one wave per node, u16x4 (8B/lane)
__global__ __launch_bounds__(256) void spmm_bf16_256(
    const int* __restrict__ rp, const int2* __restrict__ payload,
    const unsigned short* __restrict__ X, unsigned short* __restrict__ Y, int n) {
    int node = blockIdx.x * 4 + (threadIdx.x >> 6);
    if (node >= n) return;
    int lane = threadIdx.x & 63;
    const unsigned short* Xo = X + lane * 4;
    int beg = rp[node], end = rp[node + 1];
    float acc[4] = {};
    for (int e = beg; e < end; e += 8) {
        int2 p[8];
#pragma unroll
        for (int j = 0; j < 8; j++) p[j] = payload[e + j];
        u16x4_t v[8];
#pragma unroll
        for (int j = 0; j < 8; j++) v[j] = *(const u16x4_t*)(Xo + (size_t)p[j].x * 256);
#pragma unroll
        for (int j = 0; j < 8; j++) {
            float w = __int_as_float(p[j].y);
#pragma unroll
            for (int c = 0; c < 4; c++) acc[c] += w * bf2f(v[j][c]);
        }
    }
    u16x4_t o;
#pragma unroll
    for (int c = 0; c < 4; c++) o[c] = f2bf(acc[c]);
    *(u16x4_t*)(Y + (size_t)node * 256 + lane * 4) = o;
}

// ---------------- z path ----------------

__global__ __launch_bounds__(256) void z_gather(const int* __restrict__ rp,
                                                const int2* __restrict__ payload,
                                                const float* __restrict__ z,
                                                const float* __restrict__ nd, const float* __restrict__ b3,
                                                float* __restrict__ o, int n) {
    int d = blockIdx.x * 4 + (threadIdx.x >> 6);
    if (d >= n) return;
    int lane = threadIdx.x & 63;
    int beg = rp[d], end = rp[d + 1];
    float acc = 0.f;
    for (int e = beg + lane; e < end; e += 64) {
        int2 p = payload[e];
        acc += __int_as_float(p.y) * z[p.x];
    }
    for (int off = 32; off > 0; off >>= 1) acc += __shfl_down(acc, off);
    if (lane == 0) o[d] = fmaxf(nd[d] * acc + b3[0], 0.f);
}

// ---------------- launch ----------------

extern "C" void kernel_launch(void* const* d_in, const int* in_sizes, int n_in,
                              void* d_out, int out_size, void* d_ws, size_t ws_size,
                              hipStream_t stream) {
    const float* class_embed = (const float*)d_in[0];
    const float* all_glove   = (const float*)d_in[1];
    const float* W_word = (const float*)d_in[2];
    const float* b_word = (const float*)d_in[3];
    const float* W_img  = (const float*)d_in[4];
    const float* b_img  = (const float*)d_in[5];
    const float* W1 = (const float*)d_in[6];
    const float* b1 = (const float*)d_in[7];
    const float* W2 = (const float*)d_in[8];
    const float* b2 = (const float*)d_in[9];
    const float* W3 = (const float*)d_in[10];
    const float* b3 = (const float*)d_in[11];
    const float* W_fin = (const float*)d_in[12];
    const float* b_fin = (const float*)d_in[13];
    const int* src = (const int*)d_in[14];
    const int* dst = (const int*)d_in[15];

    const int N   = in_sizes[0];
    const int GLV = in_sizes[1] / N;   // 300
    const int FD  = in_sizes[5];       // 254
    const int IF  = in_sizes[7];       // 508
    const int E   = in_sizes[14];

    const int GLVp = 320;
    const int FDp  = 256;
    const int IFp  = 512;
    const int Mp   = (N + 63) & ~63;
    const int EP   = E + 8 * N;
    const int nhalf = (N + 1) / 2;
    const int chunk = (E + NB_E - 1) / NB_E;
    const int nch   = (N >> ASHIFT) + 1;          // src-chunks (<=16)
    const int chunkE = (E + NBLK_A - 1) / NBLK_A;

    char* base = (char*)d_ws;
    size_t off = 0;
    auto alloc = [&](size_t bytes) -> void* {
        void* p = base + off;
        off = (off + bytes + 255) & ~(size_t)255;
        return p;
    };

    float* z   = (float*)alloc((size_t)N * 4);
    float* ce  = (float*)alloc((size_t)FD * 4);
    size_t zero_bytes = (size_t)((char*)(ce + FD) - (char*)z);
    float* ns  = (float*)alloc((size_t)N * 4);
    float* nd  = (float*)alloc((size_t)N * 4);
    float* tv  = (float*)alloc((size_t)N * 4);
    float* u   = (float*)alloc((size_t)IF * 4);
    float* ov  = (float*)alloc((size_t)N * 4);
    int* degp  = (int*)alloc((size_t)N * 4);
    int* rp    = (int*)alloc((size_t)(N + 1) * 4);
    int* bsum  = (int*)alloc(64 * 4);
    int* acnt  = (int*)alloc((size_t)16 * NBLK_A * 4);
    int* src2  = (int*)alloc((size_t)E * 4);
    int* dst2  = (int*)alloc((size_t)E * 4);
    int* histD = (int*)alloc((size_t)NB_E * N * 4);
    int* histS = (int*)alloc((size_t)NB_E * N * 4);
    int* gbase = (int*)alloc((size_t)NB_E * N * 4);
    int2* payload = (int2*)alloc((size_t)EP * 8);
    unsigned short* WwP  = (unsigned short*)alloc((size_t)FDp * GLVp * 2);
    unsigned short* W1hT = (unsigned short*)alloc((size_t)IFp * FDp * 2);
    unsigned short* W2T  = (unsigned short*)alloc((size_t)IFp * IFp * 2);
    unsigned short* glove_bf = (unsigned short*)alloc((size_t)Mp * GLVp * 2);
    unsigned short* we       = (unsigned short*)alloc((size_t)Mp * FDp * 2);
    unsigned short* h12      = (unsigned short*)alloc((size_t)Mp * IFp * 2);
    unsigned short* aggwe = glove_bf;
    unsigned short* agg2  = glove_bf;
    unsigned short* h1 = h12;

    hipMemsetAsync(z, 0, zero_bytes, stream);
    hipMemsetAsync(payload, 0, (size_t)EP * 8, stream);
    hipMemsetAsync(d_out, 0, (size_t)FD * 4, stream);

    int gN = (N + TPB - 1) / TPB;
    int nb = (N + 1023) / 1024;

    // pass A: sort edges by src-chunk (L2-locality for SpMM gathers)
    sortA_count<<<NBLK_A, 1024, 0, stream>>>(src, acnt, E, nch, chunkE);
    sortA_scan<<<1, 1024, 0, stream>>>(acnt, nch * NBLK_A);
    sortA_scatter<<<NBLK_A, 1024, 0, stream>>>(src, dst, acnt, src2, dst2, E, nch, chunkE);

    // CSR build on sorted edges: hist -> degrees/norms -> scan -> gbase -> rank-scatter
    {
        dim3 g(NB_E, 4);
        hist_kernel<<<g, HTPB, 0, stream>>>(src2, dst2, histD, histS, E, N, nhalf, chunk);
    }
    degreduce_kernel<<<gN, TPB, 0, stream>>>(histD, histS, ns, nd, degp, N);
    scan1<<<nb, 1024, 0, stream>>>(degp, rp, bsum, N);
    scan2<<<1, 64, 0, stream>>>(bsum, nb);
    scan3<<<nb, 1024, 0, stream>>>(rp, bsum, N);
    gbase_kernel<<<gN, TPB, 0, stream>>>(histD, rp, gbase, N);
    {
        dim3 g(NB_E, 2);
        scatter2_kernel<<<g, HTPB, 0, stream>>>(src2, dst2, gbase, ns, payload, E, N, nhalf, chunk);
    }
    st_kernel<<<(N + 3) / 4, 256, 0, stream>>>(rp, payload, nd, tv, N);

    // ce = class_embed @ W_img.T + b_img  (split-n, atomic) ; u = ce @ W1[:FD, :]
    {
        dim3 g(FD, 8);
        gemv_rows_split<<<g, TPB, 0, stream>>>(class_embed, W_img, b_img, ce, N, 8);
    }
    u_kernel<<<IF, 64, 0, stream>>>(ce, W1, u, FD, IF);

    // conversions
    {
        int cpr = GLVp / 4;
        int tot = Mp * cpr;
        pad_convert4<<<(tot + 255) / 256, 256, 0, stream>>>(all_glove, GLV, N, glove_bf, GLVp, Mp, cpr);
        int tot2 = FDp * cpr;
        pad_convert4<<<(tot2 + 255) / 256, 256, 0, stream>>>(W_word, GLV, FD, WwP, GLVp, FDp, cpr);
    }
    {
        dim3 g(FDp / 32, IFp / 32);
        transpose_pad<<<g, dim3(32, 8), 0, stream>>>(W1 + (size_t)FD * IF, FD, IF, IF, W1hT, IFp, FDp);
    }
    {
        dim3 g(IFp / 32, IFp / 32);
        transpose_pad<<<g, dim3(32, 8), 0, stream>>>(W2, IF, IF, IF, W2T, IFp, IFp);
    }

    int mtiles = Mp / 64;

    // we = all_glove @ W_word.T + b_word   [N][256] bf16
    {
        dim3 g(FDp / 64, mtiles);
        mfma_gemm<<<g, 256, 0, stream>>>(glove_bf, WwP, b_word, nullptr, nullptr, nullptr,
                                         nullptr, nullptr, we, N, FD, GLVp, FDp, 0);
    }
    // SpMM1: aggwe = sum w*we[s]   [N][256]
    spmm_bf16_256<<<(N + 3) / 4, 256, 0, stream>>>(rp, payload, we, aggwe, N);
    // h1 = relu(nd[r]*(aggwe @ W1[FD:,:]) + tv[r]*u[c] + b1)   [N][512]
    {
        dim3 g(IFp / 64, mtiles);
        mfma_gemm<<<g, 256, 0, stream>>>(aggwe, W1hT, b1, nd, tv, u,
                                         nullptr, nullptr, h1, N, IF, FDp, IFp, 1);
    }
    // SpMM2: agg2 = sum w*h1[s]   [N][512]  (single pass, sorted gathers)
    spmm_bf16_512<<<(N + 3) / 4, 256, 0, stream>>>(rp, payload, h1, agg2, N);
    // gemm2 fused: z[r] = relu(nd[r]*(agg2 @ W2) + b2) @ W3
    {
        dim3 g(IFp / 64, mtiles);
        mfma_gemm<<<g, 256, 0, stream>>>(agg2, W2T, b2, nd, nullptr, nullptr,
                                         W3, z, nullptr, N, IF, IFp, IFp, 1);
    }
    // o = relu(nd * gather(w*z) + b3)
    z_gather<<<(N + 3) / 4, 256, 0, stream>>>(rp, payload, z, nd, b3, ov, N);
    // out = o @ W_fin.T + b_fin
    {
        dim3 g(FD, 8);
        gemv_rows_split<<<g, TPB, 0, stream>>>(ov, W_fin, b_fin, (float*)d_out, N, 8);
    }
}

// Round 14
// 327.137 us; speedup vs baseline: 1.0425x; 1.0425x over previous
//
#include <hip/hip_runtime.h>
#include <hip/hip_bf16.h>

#define TPB 256
#define NB_E 32          // edge chunks for counting sort
#define HTPB 512         // threads per hist/scatter block
#define NHALF_LDS 10240  // LDS histogram capacity (ints) per half-range

typedef __attribute__((ext_vector_type(8))) short bf16x8_t;
typedef __attribute__((ext_vector_type(4))) float f32x4_t;
typedef __attribute__((ext_vector_type(8))) unsigned short u16x8_t;
typedef __attribute__((ext_vector_type(4))) unsigned short u16x4_t;

__device__ __forceinline__ float bf2f(unsigned short u) {
    return __uint_as_float(((unsigned)u) << 16);
}
__device__ __forceinline__ unsigned short f2bf(float f) {
    unsigned x = __float_as_uint(f);
    unsigned r = (x + 0x7fff + ((x >> 16) & 1)) >> 16;  // RNE
    return (unsigned short)r;
}

// async global -> LDS, 16 bytes per lane
__device__ __forceinline__ void gload16(const unsigned short* g, unsigned short* l) {
    __builtin_amdgcn_global_load_lds(
        (const __attribute__((address_space(1))) unsigned int*)(const void*)g,
        (__attribute__((address_space(3))) unsigned int*)(void*)l, 16, 0, 0);
}

// ---------------- CSR build via counting sort (no global atomics) ----------------

__global__ __launch_bounds__(HTPB) void hist_kernel(
    const int* __restrict__ src, const int* __restrict__ dst,
    int* __restrict__ histD, int* __restrict__ histS,
    int E, int N, int nhalf, int chunk) {
    __shared__ int h[NHALF_LDS];
    int b = blockIdx.x, var = blockIdx.y;
    const int* arr = (var < 2) ? dst : src;
    int lo = (var & 1) * nhalf;
    int hi = min(lo + nhalf, N);
    int cnt = hi - lo;
    for (int i = threadIdx.x; i < cnt; i += HTPB) h[i] = 0;
    __syncthreads();
    int beg = b * chunk, end = min(E, beg + chunk);
    for (int i = beg + threadIdx.x; i < end; i += HTPB) {
        int v = arr[i];
        if (v >= lo && v < hi) atomicAdd(&h[v - lo], 1);
    }
    __syncthreads();
    int* out = ((var < 2) ? histD : histS) + (size_t)b * N + lo;
    for (int i = threadIdx.x; i < cnt; i += HTPB) out[i] = h[i];
}

__global__ void degreduce_kernel(const int* __restrict__ histD, const int* __restrict__ histS,
                                 float* __restrict__ ns, float* __restrict__ nd,
                                 int* __restrict__ degp, int N) {
    int n = blockIdx.x * blockDim.x + threadIdx.x;
    if (n >= N) return;
    int di = 0, dout = 0;
    for (int b = 0; b < NB_E; b++) {
        di += histD[(size_t)b * N + n];
        dout += histS[(size_t)b * N + n];
    }
    nd[n] = di > 0 ? rsqrtf((float)di) : 0.f;
    ns[n] = dout > 0 ? rsqrtf((float)dout) : 0.f;
    degp[n] = (di + 7) & ~7;  // pad each list to multiple of 8
}

__global__ __launch_bounds__(1024) void scan1(const int* __restrict__ degp,
                                              int* __restrict__ rp, int* __restrict__ bsum, int n) {
    __shared__ int buf[1024];
    int b = blockIdx.x;
    int i = b * 1024 + threadIdx.x;
    int v = (i < n) ? degp[i] : 0;
    buf[threadIdx.x] = v;
    __syncthreads();
    for (int off = 1; off < 1024; off <<= 1) {
        int t = (threadIdx.x >= off) ? buf[threadIdx.x - off] : 0;
        __syncthreads();
        buf[threadIdx.x] += t;
        __syncthreads();
    }
    if (i < n) rp[i + 1] = buf[threadIdx.x];
    if (threadIdx.x == 1023) bsum[b] = buf[1023];
    if (b == 0 && threadIdx.x == 0) rp[0] = 0;
}

__global__ void scan2(int* __restrict__ bsum, int nb) {
    int lane = threadIdx.x;
    int v = (lane < nb) ? bsum[lane] : 0;
    for (int off = 1; off < 64; off <<= 1) {
        int t = __shfl_up(v, off);
        if (lane >= off) v += t;
    }
    if (lane < nb) bsum[lane] = v;
}

__global__ __launch_bounds__(1024) void scan3(int* __restrict__ rp, const int* __restrict__ bsum, int n) {
    int b = blockIdx.x;
    if (b == 0) return;
    int i = b * 1024 + threadIdx.x;
    if (i < n) rp[i + 1] += bsum[b - 1];
}

__global__ void gbase_kernel(const int* __restrict__ histD, const int* __restrict__ rp,
                             int* __restrict__ gbase, int N) {
    int n = blockIdx.x * blockDim.x + threadIdx.x;
    if (n >= N) return;
    int run = rp[n];
    for (int b = 0; b < NB_E; b++) {
        gbase[(size_t)b * N + n] = run;
        run += histD[(size_t)b * N + n];
    }
}

__global__ __launch_bounds__(HTPB) void scatter2_kernel(
    const int* __restrict__ src, const int* __restrict__ dst,
    const int* __restrict__ gbase, const float* __restrict__ ns,
    int2* __restrict__ payload, int E, int N, int nhalf, int chunk) {
    __shared__ int h[NHALF_LDS];
    int b = blockIdx.x, half = blockIdx.y;
    int lo = half * nhalf;
    int hi = min(lo + nhalf, N);
    int cnt = hi - lo;
    for (int i = threadIdx.x; i < cnt; i += HTPB) h[i] = 0;
    __syncthreads();
    int beg = b * chunk, end = min(E, beg + chunk);
    for (int i = beg + threadIdx.x; i < end; i += HTPB) {
        int d = dst[i];
        if (d >= lo && d < hi) {
            int s = src[i];
            int rank = atomicAdd(&h[d - lo], 1);
            int pos = gbase[(size_t)b * N + d] + rank;
            payload[pos] = make_int2(s, __float_as_int(ns[s]));
        }
    }
}

// t[d] = nd[d] * sum_e w_e   (padding has w=0)
__global__ __launch_bounds__(256) void st_kernel(const int* __restrict__ rp,
                                                 const int2* __restrict__ payload,
                                                 const float* __restrict__ nd,
                                                 float* __restrict__ tv, int n) {
    int d = blockIdx.x * 4 + (threadIdx.x >> 6);
    if (d >= n) return;
    int lane = threadIdx.x & 63;
    int beg = rp[d], end = rp[d + 1];
    float acc = 0.f;
    for (int e = beg + lane; e < end; e += 64) acc += __int_as_float(payload[e].y);
    for (int off = 32; off > 0; off >>= 1) acc += __shfl_down(acc, off);
    if (lane == 0) tv[d] = acc * nd[d];
}

// ---------------- small GEMV (fp32) ----------------

// split-n: out[j] += partial dot; out must be pre-zeroed; slice 0 adds bias
__global__ void gemv_rows_split(const float* __restrict__ vec, const float* __restrict__ Mat,
                                const float* __restrict__ bias, float* __restrict__ out,
                                int n, int nslices) {
    int j = blockIdx.x, slice = blockIdx.y;
    int len = (n + nslices - 1) / nslices;
    int beg = slice * len, end = min(n, beg + len);
    const float* row = Mat + (size_t)j * n;
    float s = 0.f;
    for (int i = beg + threadIdx.x; i < end; i += blockDim.x) s += vec[i] * row[i];
    __shared__ float red[TPB];
    red[threadIdx.x] = s;
    __syncthreads();
    for (int o = TPB / 2; o > 0; o >>= 1) {
        if (threadIdx.x < o) red[threadIdx.x] += red[threadIdx.x + o];
        __syncthreads();
    }
    if (threadIdx.x == 0) {
        float v = red[0] + ((slice == 0 && bias) ? bias[j] : 0.f);
        atomicAdd(&out[j], v);
    }
}

__global__ __launch_bounds__(64) void u_kernel(const float* __restrict__ ce, const float* __restrict__ W1,
                                               float* __restrict__ u, int FD, int IF) {
    int j = blockIdx.x;
    int lane = threadIdx.x;
    float s = 0.f;
    for (int i = lane; i < FD; i += 64) s += ce[i] * W1[(size_t)i * IF + j];
    for (int off = 32; off > 0; off >>= 1) s += __shfl_down(s, off);
    if (lane == 0) u[j] = s;
}

// ---------------- conversion kernels ----------------

__global__ void pad_convert4(const float* __restrict__ in, int icols, int irows,
                             unsigned short* __restrict__ out, int ocols, int orows, int cpr) {
    int idx = blockIdx.x * blockDim.x + threadIdx.x;
    int row = idx / cpr;
    int c4 = (idx - row * cpr) * 4;
    if (row >= orows) return;
    float4 v = make_float4(0.f, 0.f, 0.f, 0.f);
    if (row < irows && c4 < icols)
        v = *(const float4*)(in + (size_t)row * icols + c4);
    u16x4_t o;
    o[0] = f2bf(v.x); o[1] = f2bf(v.y); o[2] = f2bf(v.z); o[3] = f2bf(v.w);
    *(u16x4_t*)(out + (size_t)row * ocols + c4) = o;
}

__global__ void transpose_pad(const float* __restrict__ W, int rows, int cols, int ldw,
                              unsigned short* __restrict__ out, int orows, int ocols) {
    __shared__ float tile[32][33];
    int k0 = blockIdx.x * 32, n0 = blockIdx.y * 32;
    int tx = threadIdx.x, ty = threadIdx.y;  // 32 x 8
    for (int i = 0; i < 32; i += 8) {
        int k = k0 + ty + i, n = n0 + tx;
        tile[ty + i][tx] = (k < rows && n < cols) ? W[(size_t)k * ldw + n] : 0.f;
    }
    __syncthreads();
    for (int i = 0; i < 32; i += 8) {
        int n = n0 + ty + i, k = k0 + tx;
        if (n < orows && k < ocols) out[(size_t)n * ocols + k] = f2bf(tile[tx][ty + i]);
    }
}

// ---------------- bf16 MFMA GEMM (64x64 tile, high-occupancy TLP) ----------------
// 2x2 waves of 32x32 each; LDS 16KB dbuf -> ~10 blocks/CU; grid ~2500 blocks.
// A padded to gridDim.y*64 rows. XCD-aware bijective block swizzle.
__global__ __launch_bounds__(256) void mfma_gemm(
    const unsigned short* __restrict__ A, const unsigned short* __restrict__ Bt,
    const float* __restrict__ bias, const float* __restrict__ rowscale,
    const float* __restrict__ tvec, const float* __restrict__ uvec,
    const float* __restrict__ w3, float* __restrict__ zout,
    unsigned short* __restrict__ C, int M, int Nn, int Kp, int Cld, int relu) {
    __shared__ unsigned short As[2][64 * 32];
    __shared__ unsigned short Bs[2][64 * 32];
    int tid = threadIdx.x;
    int lane = tid & 63;
    int wave = tid >> 6;
    int wm = wave >> 1, wn = wave & 1;  // 2x2 waves, each 32x32
    int lg = lane >> 4, lt = lane & 15;

    // bijective XCD swizzle (m204)
    int nwg = gridDim.x * gridDim.y;
    int hid = blockIdx.y * gridDim.x + blockIdx.x;
    int q = nwg >> 3, r8 = nwg & 7;
    int xcd = hid & 7, pos = hid >> 3;
    int wg = (xcd < r8 ? xcd * (q + 1) : r8 * (q + 1) + (xcd - r8) * q) + pos;
    int row0 = (wg / gridDim.x) * 64, col0 = (wg % gridDim.x) * 64;

    f32x4_t acc[2][2] = {};

    // staging: 256 chunks of 16B per operand, 1 chunk/thread each
    int sr = tid >> 2, sc = tid & 3;
    int ssw = sc ^ ((sr >> 1) & 3);  // pre-swizzle SOURCE; LDS dest linear
    const unsigned short* gA = A + (size_t)(row0 + sr) * Kp + (ssw << 3);
    const unsigned short* gB = Bt + (size_t)(col0 + sr) * Kp + (ssw << 3);

    int nk = Kp >> 5;
    gload16(gA, As[0] + tid * 8);
    gload16(gB, Bs[0] + tid * 8);
    __syncthreads();

    int cur = 0;
    for (int kp = 0; kp < nk; kp++) {
        if (kp + 1 < nk) {
            int k0 = (kp + 1) << 5;
            gload16(gA + k0, As[cur ^ 1] + tid * 8);
            gload16(gB + k0, Bs[cur ^ 1] + tid * 8);
        }
        bf16x8_t af[2], bfr[2];
#pragma unroll
        for (int mi = 0; mi < 2; mi++) {
            int r = wm * 32 + mi * 16 + lt;
            int sw = lg ^ ((r >> 1) & 3);
            af[mi] = *(const bf16x8_t*)(As[cur] + r * 32 + sw * 8);
        }
#pragma unroll
        for (int ni = 0; ni < 2; ni++) {
            int r = wn * 32 + ni * 16 + lt;
            int sw = lg ^ ((r >> 1) & 3);
            bfr[ni] = *(const bf16x8_t*)(Bs[cur] + r * 32 + sw * 8);
        }
#pragma unroll
        for (int mi = 0; mi < 2; mi++)
#pragma unroll
            for (int ni = 0; ni < 2; ni++)
                acc[mi][ni] = __builtin_amdgcn_mfma_f32_16x16x32_bf16(af[mi], bfr[ni], acc[mi][ni], 0, 0, 0);
        __syncthreads();
        cur ^= 1;
    }

#pragma unroll
    for (int mi = 0; mi < 2; mi++) {
#pragma unroll
        for (int r = 0; r < 4; r++) {
            int row = row0 + wm * 32 + mi * 16 + lg * 4 + r;
            if (row >= M) continue;
            float rs = rowscale ? rowscale[row] : 1.f;
            float tvr = tvec ? tvec[row] : 0.f;
            float zp = 0.f;
#pragma unroll
            for (int ni = 0; ni < 2; ni++) {
                int colb = col0 + wn * 32 + ni * 16 + lt;
                float v = 0.f;
                if (colb < Nn) {
                    v = acc[mi][ni][r] * rs;
                    if (bias) v += bias[colb];
                    if (tvec) v += tvr * uvec[colb];
                    if (relu) v = fmaxf(v, 0.f);
                    if (w3) zp += v * w3[colb];
                }
                if (C) C[(size_t)row * Cld + colb] = f2bf(v);
            }
            if (w3) {
                zp += __shfl_xor(zp, 1);
                zp += __shfl_xor(zp, 2);
                zp += __shfl_xor(zp, 4);
                zp += __shfl_xor(zp, 8);
                if (lt == 0) atomicAdd(&zout[row], zp);
            }
        }
    }
}

// ---------------- SpMM (CSR gather, payload, 8-edge unroll, tail-free) ----------------
__global__ __launch_bounds__(256) void spmm_bf16_cols(
    const int* __restrict__ rp, const int2* __restrict__ payload,
    const unsigned short* __restrict__ X, unsigned short* __restrict__ Y,
    int n, int ld, int c0) {
    int node = blockIdx.x * 4 + (threadIdx.x >> 6);
    if (node >= n) return;
    int lane = threadIdx.x & 63;
    const unsigned short* Xo = X + c0 + lane * 4;
    int beg = rp[node], end = rp[node + 1];
    float acc[4] = {};
    for (int e = beg; e < end; e += 8) {
        int2 p[8];
#pragma unroll
        for (int j = 0; j < 8; j++) p[j] = payload[e + j];
        u16x4_t v[8];
#pragma unroll
        for (int j = 0; j < 8; j++) v[j] = *(const u16x4_t*)(Xo + (size_t)p[j].x * ld);
#pragma unroll
        for (int j = 0; j < 8; j++) {
            float w = __int_as_float(p[j].y);
#pragma unroll
            for (int c = 0; c < 4; c++) acc[c] += w * bf2f(v[j][c]);
        }
    }
    u16x4_t o;
#pragma unroll
    for (int c = 0; c < 4; c++) o[c] = f2bf(acc[c]);
    *(u16x4_t*)(Y + (size_t)node * ld + c0 + lane * 4) = o;
}

// ---------------- z path ----------------

__global__ __launch_bounds__(256) void z_gather(const int* __restrict__ rp,
                                                const int2* __restrict__ payload,
                                                const float* __restrict__ z,
                                                const float* __restrict__ nd, const float* __restrict__ b3,
                                                float* __restrict__ o, int n) {
    int d = blockIdx.x * 4 + (threadIdx.x >> 6);
    if (d >= n) return;
    int lane = threadIdx.x & 63;
    int beg = rp[d], end = rp[d + 1];
    float acc = 0.f;
    for (int e = beg + lane; e < end; e += 64) {
        int2 p = payload[e];
        acc += __int_as_float(p.y) * z[p.x];
    }
    for (int off = 32; off > 0; off >>= 1) acc += __shfl_down(acc, off);
    if (lane == 0) o[d] = fmaxf(nd[d] * acc + b3[0], 0.f);
}

// ---------------- launch ----------------

extern "C" void kernel_launch(void* const* d_in, const int* in_sizes, int n_in,
                              void* d_out, int out_size, void* d_ws, size_t ws_size,
                              hipStream_t stream) {
    const float* class_embed = (const float*)d_in[0];
    const float* all_glove   = (const float*)d_in[1];
    const float* W_word = (const float*)d_in[2];
    const float* b_word = (const float*)d_in[3];
    const float* W_img  = (const float*)d_in[4];
    const float* b_img  = (const float*)d_in[5];
    const float* W1 = (const float*)d_in[6];
    const float* b1 = (const float*)d_in[7];
    const float* W2 = (const float*)d_in[8];
    const float* b2 = (const float*)d_in[9];
    const float* W3 = (const float*)d_in[10];
    const float* b3 = (const float*)d_in[11];
    const float* W_fin = (const float*)d_in[12];
    const float* b_fin = (const float*)d_in[13];
    const int* src = (const int*)d_in[14];
    const int* dst = (const int*)d_in[15];

    const int N   = in_sizes[0];
    const int GLV = in_sizes[1] / N;   // 300
    const int FD  = in_sizes[5];       // 254
    const int IF  = in_sizes[7];       // 508
    const int E   = in_sizes[14];

    const int GLVp = 320;
    const int FDp  = 256;
    const int IFp  = 512;
    const int Mp   = (N + 63) & ~63;       // padded row count for GEMM A operands
    const int EP   = E + 8 * N;            // padded edge capacity
    const int nhalf = (N + 1) / 2;         // <= NHALF_LDS
    const int chunk = (E + NB_E - 1) / NB_E;

    char* base = (char*)d_ws;
    size_t off = 0;
    auto alloc = [&](size_t bytes) -> void* {
        void* p = base + off;
        off = (off + bytes + 255) & ~(size_t)255;
        return p;
    };

    // zeroed region: z (atomic accum) + ce (atomic accum), contiguous
    float* z   = (float*)alloc((size_t)N * 4);
    float* ce  = (float*)alloc((size_t)FD * 4);
    size_t zero_bytes = (size_t)((char*)(ce + FD) - (char*)z);
    float* ns  = (float*)alloc((size_t)N * 4);
    float* nd  = (float*)alloc((size_t)N * 4);
    float* tv  = (float*)alloc((size_t)N * 4);
    float* u   = (float*)alloc((size_t)IF * 4);
    float* ov  = (float*)alloc((size_t)N * 4);
    int* degp  = (int*)alloc((size_t)N * 4);
    int* rp    = (int*)alloc((size_t)(N + 1) * 4);
    int* bsum  = (int*)alloc(64 * 4);
    int* histD = (int*)alloc((size_t)NB_E * N * 4);
    int* histS = (int*)alloc((size_t)NB_E * N * 4);
    int* gbase = (int*)alloc((size_t)NB_E * N * 4);
    int2* payload = (int2*)alloc((size_t)EP * 8);
    unsigned short* WwP  = (unsigned short*)alloc((size_t)FDp * GLVp * 2);
    unsigned short* W1hT = (unsigned short*)alloc((size_t)IFp * FDp * 2);
    unsigned short* W2T  = (unsigned short*)alloc((size_t)IFp * IFp * 2);
    unsigned short* glove_bf = (unsigned short*)alloc((size_t)Mp * GLVp * 2);
    unsigned short* we       = (unsigned short*)alloc((size_t)Mp * FDp * 2);
    unsigned short* h12      = (unsigned short*)alloc((size_t)Mp * IFp * 2);
    unsigned short* aggwe = glove_bf;   // [Mp][256] after glove dead
    unsigned short* agg2  = glove_bf;   // [Mp][512] spans glove+we regions
    unsigned short* h1 = h12;

    hipMemsetAsync(z, 0, zero_bytes, stream);                // z + ce
    hipMemsetAsync(payload, 0, (size_t)EP * 8, stream);      // padding edges {s=0,w=0}
    hipMemsetAsync(d_out, 0, (size_t)FD * 4, stream);        // final out (atomic accum)

    int gN = (N + TPB - 1) / TPB;
    int nb = (N + 1023) / 1024;

    // CSR build: hist -> degrees/norms -> scan -> gbase -> rank-scatter
    {
        dim3 g(NB_E, 4);
        hist_kernel<<<g, HTPB, 0, stream>>>(src, dst, histD, histS, E, N, nhalf, chunk);
    }
    degreduce_kernel<<<gN, TPB, 0, stream>>>(histD, histS, ns, nd, degp, N);
    scan1<<<nb, 1024, 0, stream>>>(degp, rp, bsum, N);
    scan2<<<1, 64, 0, stream>>>(bsum, nb);
    scan3<<<nb, 1024, 0, stream>>>(rp, bsum, N);
    gbase_kernel<<<gN, TPB, 0, stream>>>(histD, rp, gbase, N);
    {
        dim3 g(NB_E, 2);
        scatter2_kernel<<<g, HTPB, 0, stream>>>(src, dst, gbase, ns, payload, E, N, nhalf, chunk);
    }
    st_kernel<<<(N + 3) / 4, 256, 0, stream>>>(rp, payload, nd, tv, N);

    // ce = class_embed @ W_img.T + b_img  (split-n, atomic) ; u = ce @ W1[:FD, :]
    {
        dim3 g(FD, 8);
        gemv_rows_split<<<g, TPB, 0, stream>>>(class_embed, W_img, b_img, ce, N, 8);
    }
    u_kernel<<<IF, 64, 0, stream>>>(ce, W1, u, FD, IF);

    // conversions (glove zero-padded to Mp rows so GEMM A-stage needs no M guard)
    {
        int cpr = GLVp / 4;
        int tot = Mp * cpr;
        pad_convert4<<<(tot + 255) / 256, 256, 0, stream>>>(all_glove, GLV, N, glove_bf, GLVp, Mp, cpr);
        int tot2 = FDp * cpr;
        pad_convert4<<<(tot2 + 255) / 256, 256, 0, stream>>>(W_word, GLV, FD, WwP, GLVp, FDp, cpr);
    }
    {
        dim3 g(FDp / 32, IFp / 32);
        transpose_pad<<<g, dim3(32, 8), 0, stream>>>(W1 + (size_t)FD * IF, FD, IF, IF, W1hT, IFp, FDp);
    }
    {
        dim3 g(IFp / 32, IFp / 32);
        transpose_pad<<<g, dim3(32, 8), 0, stream>>>(W2, IF, IF, IF, W2T, IFp, IFp);
    }

    int mtiles = Mp / 64;

    // we = all_glove @ W_word.T + b_word   [N][256] bf16
    {
        dim3 g(FDp / 64, mtiles);
        mfma_gemm<<<g, 256, 0, stream>>>(glove_bf, WwP, b_word, nullptr, nullptr, nullptr,
                                         nullptr, nullptr, we, N, FD, GLVp, FDp, 0);
    }
    // SpMM1: aggwe = sum w*we[s]   [N][256]
    spmm_bf16_cols<<<(N + 3) / 4, 256, 0, stream>>>(rp, payload, we, aggwe, N, FDp, 0);
    // h1 = relu(nd[r]*(aggwe @ W1[FD:,:]) + tv[r]*u[c] + b1)   [N][512]
    {
        dim3 g(IFp / 64, mtiles);
        mfma_gemm<<<g, 256, 0, stream>>>(aggwe, W1hT, b1, nd, tv, u,
                                         nullptr, nullptr, h1, N, IF, FDp, IFp, 1);
    }
    // SpMM2: agg2 = sum w*h1[s]   [N][512]  (two column passes)
    spmm_bf16_cols<<<(N + 3) / 4, 256, 0, stream>>>(rp, payload, h1, agg2, N, IFp, 0);
    spmm_bf16_cols<<<(N + 3) / 4, 256, 0, stream>>>(rp, payload, h1, agg2, N, IFp, 256);
    // gemm2 fused: z[r] = relu(nd[r]*(agg2 @ W2) + b2) @ W3   (no C write)
    {
        dim3 g(IFp / 64, mtiles);
        mfma_gemm<<<g, 256, 0, stream>>>(agg2, W2T, b2, nd, nullptr, nullptr,
                                         W3, z, nullptr, N, IF, IFp, IFp, 1);
    }
    // o = relu(nd * gather(w*z) + b3)
    z_gather<<<(N + 3) / 4, 256, 0, stream>>>(rp, payload, z, nd, b3, ov, N);
    // out = o @ W_fin.T + b_fin  (split-n, atomic; d_out pre-zeroed)
    {
        dim3 g(FD, 8);
        gemv_rows_split<<<g, TPB, 0, stream>>>(ov, W_fin, b_fin, (float*)d_out, N, 8);
    }
}